// Round 1
// baseline (431.275 us; speedup 1.0000x reference)
//
#include <hip/hip_runtime.h>

#define SEQ 8192
#define DIM 1280
#define NHEADS 16
#define HD 80
#define HDP 96
#define NSEG 8
#define SEG 1024

typedef float f32x4 __attribute__((ext_vector_type(4)));
typedef short bf16x8 __attribute__((ext_vector_type(8)));

__device__ __forceinline__ short f2bf(float f) {
  unsigned int u = __builtin_bit_cast(unsigned int, f);
  u = (u + 0x7fff + ((u >> 16) & 1)) >> 16;
  return (short)u;
}

typedef __attribute__((address_space(1))) const unsigned int glds_src_t;
typedef __attribute__((address_space(3))) unsigned int glds_dst_t;
__device__ __forceinline__ void gload_lds16(const void* g, void* l) {
  __builtin_amdgcn_global_load_lds((glds_src_t*)g, (glds_dst_t*)l, 16, 0, 0);
}

// ---------------- generic f32 -> bf16 cast (vectorized) ----------------
__global__ void cast_f32_bf16(const float* __restrict__ in, short* __restrict__ out, int n) {
  int n4 = n >> 2;
  for (int i = blockIdx.x * blockDim.x + threadIdx.x; i < n4; i += gridDim.x * blockDim.x) {
    float4 v = ((const float4*)in)[i];
    short4 o;
    o.x = f2bf(v.x); o.y = f2bf(v.y); o.z = f2bf(v.z); o.w = f2bf(v.w);
    ((short4*)out)[i] = o;
  }
}

// ---------------- bf16 GEMM, B^T layout (N,K), f32 out + bias ----------------
// C[m,n] = sum_k A[m,k]*B[n,k] + bias[n].  Tile 128x128, BK=32, 4 waves.
__global__ __launch_bounds__(256) void gemm_bt_bias(
    const short* __restrict__ A, const short* __restrict__ B,
    const float* __restrict__ bias, float* __restrict__ C,
    int M, int N, int K) {
  __shared__ short As[128 * 32];
  __shared__ short Bs[128 * 32];
  int tid = threadIdx.x;
  int w = tid >> 6, l = tid & 63;
  int lrow = l & 15, lg = l >> 4;
  int m0 = blockIdx.y * 128, n0 = blockIdx.x * 128;
  int wm = w & 1, wn = w >> 1;

  f32x4 acc[4][4] = {};

  const char* Abase = (const char*)A + (size_t)m0 * K * 2;
  const char* Bbase = (const char*)B + (size_t)n0 * K * 2;

  for (int k0 = 0; k0 < K; k0 += 32) {
#pragma unroll
    for (int j = 0; j < 2; j++) {
      int c = j * 256 + tid;
      int row = c >> 2;
      int kb = (c & 3) * 16;
      size_t goff = (size_t)row * K * 2 + (size_t)k0 * 2 + kb;
      int loff = (j * 256 + w * 64) * 16;  // wave-uniform LDS base
      gload_lds16(Abase + goff, (char*)As + loff);
      gload_lds16(Bbase + goff, (char*)Bs + loff);
    }
    __syncthreads();
    bf16x8 a[4], b[4];
#pragma unroll
    for (int mt = 0; mt < 4; mt++)
      a[mt] = *(const bf16x8*)&As[(wm * 64 + mt * 16 + lrow) * 32 + lg * 8];
#pragma unroll
    for (int nt = 0; nt < 4; nt++)
      b[nt] = *(const bf16x8*)&Bs[(wn * 64 + nt * 16 + lrow) * 32 + lg * 8];
#pragma unroll
    for (int mt = 0; mt < 4; mt++)
#pragma unroll
      for (int nt = 0; nt < 4; nt++)
        acc[mt][nt] = __builtin_amdgcn_mfma_f32_16x16x32_bf16(a[mt], b[nt], acc[mt][nt], 0, 0, 0);
    __syncthreads();
  }
#pragma unroll
  for (int nt = 0; nt < 4; nt++) {
    int col = n0 + wn * 64 + nt * 16 + lrow;
    float bv = bias[col];
#pragma unroll
    for (int mt = 0; mt < 4; mt++) {
      int mrow = m0 + wm * 64 + mt * 16 + lg * 4;
#pragma unroll
      for (int r = 0; r < 4; r++)
        C[(size_t)(mrow + r) * N + col] = acc[mt][nt][r] + bv;
    }
  }
}

// ---------------- RoPE for q,k (f32 in, bf16 out, head-major, pad to 96) ----------------
__global__ void rope_qk(const float* __restrict__ qkv, const float* __restrict__ cosb,
                        const float* __restrict__ sinb, short* __restrict__ qg,
                        short* __restrict__ kg) {
  int t = blockIdx.x * blockDim.x + threadIdx.x;
  if (t >= SEQ * NHEADS * 40) return;
  int d = t % 40;
  int h = (t / 40) & 15;
  int s = t / 640;
  const float* row = qkv + (size_t)s * (3 * DIM);
  float c0 = cosb[s * HD + d], c1 = cosb[s * HD + d + 40];
  float s0 = sinb[s * HD + d], s1 = sinb[s * HD + d + 40];
  float x1 = row[h * HD + d], x2 = row[h * HD + d + 40];
  float q0 = x1 * c0 - x2 * s0;
  float q1 = x2 * c1 + x1 * s1;
  float y1 = row[DIM + h * HD + d], y2 = row[DIM + h * HD + d + 40];
  float k0 = y1 * c0 - y2 * s0;
  float k1 = y2 * c1 + y1 * s1;
  const float sc = 0.11180339887498949f;  // 80^-0.5 folded into q
  size_t base = ((size_t)h * SEQ + s) * HDP;
  qg[base + d] = f2bf(q0 * sc);
  qg[base + d + 40] = f2bf(q1 * sc);
  kg[base + d] = f2bf(k0);
  kg[base + d + 40] = f2bf(k1);
  if (d < 16) { qg[base + 80 + d] = 0; kg[base + 80 + d] = 0; }
}

// ---------------- V transpose: qkv f32 (S,3,H,80) -> vt bf16 (H,80,S) ----------------
__global__ void v_transpose(const float* __restrict__ qkv, short* __restrict__ vt) {
  __shared__ float T[16][68];
  int st = blockIdx.x, dt = blockIdx.y, h = blockIdx.z;
  int d0 = dt * 16, s0 = st * 64;
  int t = threadIdx.x;
  int dd = t & 15, ss = t >> 4;
#pragma unroll
  for (int j = 0; j < 4; j++) {
    int s = ss + j * 16;
    T[dd][s] = qkv[(size_t)(s0 + s) * (3 * DIM) + 2 * DIM + h * HD + d0 + dd];
  }
  __syncthreads();
  int s2 = t & 63, dr = t >> 6;
#pragma unroll
  for (int j = 0; j < 4; j++) {
    int d = dr + j * 4;
    vt[((size_t)(h * HD + d0 + d)) * SEQ + s0 + s2] = f2bf(T[d][s2]);
  }
}

// ---------------- flash attention: per (seg, head, qtile of 128) ----------------
// 4 independent waves, each 32 q-rows. KV step 32. K/V direct from global (L2).
__global__ __launch_bounds__(256) void attn_kernel(
    const short* __restrict__ qg, const short* __restrict__ kg,
    const short* __restrict__ vt, short* __restrict__ out) {
  __shared__ short Pl[4][32 * 40];
  int bid = blockIdx.x;
  int qt = bid & 7, h = (bid >> 3) & 15, b = bid >> 7;
  int w = threadIdx.x >> 6, l = threadIdx.x & 63;
  int lrow = l & 15, lg = l >> 4;
  int qbase_s = b * SEG + qt * 128 + w * 32;

  const short* qh = qg + (size_t)h * SEQ * HDP;
  const short* kh = kg + (size_t)h * SEQ * HDP;
  const short* vh = vt + (size_t)h * HD * SEQ;

  bf16x8 qf[2][3];
#pragma unroll
  for (int mt = 0; mt < 2; mt++)
#pragma unroll
    for (int ks = 0; ks < 3; ks++)
      qf[mt][ks] = *(const bf16x8*)&qh[(size_t)(qbase_s + mt * 16 + lrow) * HDP + ks * 32 + lg * 8];

  f32x4 o[2][5] = {};
  float m_st[2][4], l_st[2][4];
#pragma unroll
  for (int mt = 0; mt < 2; mt++)
#pragma unroll
    for (int r = 0; r < 4; r++) { m_st[mt][r] = -1e30f; l_st[mt][r] = 0.f; }

  short* Pw = &Pl[w][0];

  for (int kv = 0; kv < SEG; kv += 32) {
    int key0 = b * SEG + kv;
    bf16x8 kf[2][3];
#pragma unroll
    for (int kt = 0; kt < 2; kt++)
#pragma unroll
      for (int ks = 0; ks < 3; ks++)
        kf[kt][ks] = *(const bf16x8*)&kh[(size_t)(key0 + kt * 16 + lrow) * HDP + ks * 32 + lg * 8];
    f32x4 s[2][2] = {};
#pragma unroll
    for (int mt = 0; mt < 2; mt++)
#pragma unroll
      for (int kt = 0; kt < 2; kt++)
#pragma unroll
        for (int ks = 0; ks < 3; ks++)
          s[mt][kt] = __builtin_amdgcn_mfma_f32_16x16x32_bf16(qf[mt][ks], kf[kt][ks], s[mt][kt], 0, 0, 0);

#pragma unroll
    for (int mt = 0; mt < 2; mt++) {
#pragma unroll
      for (int r = 0; r < 4; r++) {
        float cm = fmaxf(s[mt][0][r], s[mt][1][r]);
        cm = fmaxf(cm, __shfl_xor(cm, 1));
        cm = fmaxf(cm, __shfl_xor(cm, 2));
        cm = fmaxf(cm, __shfl_xor(cm, 4));
        cm = fmaxf(cm, __shfl_xor(cm, 8));
        float mo = m_st[mt][r];
        float mn = fmaxf(mo, cm);
        float c = __expf(mo - mn);
        m_st[mt][r] = mn;
        float p0 = __expf(s[mt][0][r] - mn);
        float p1 = __expf(s[mt][1][r] - mn);
        float rs = p0 + p1;
        rs += __shfl_xor(rs, 1);
        rs += __shfl_xor(rs, 2);
        rs += __shfl_xor(rs, 4);
        rs += __shfl_xor(rs, 8);
        l_st[mt][r] = l_st[mt][r] * c + rs;
#pragma unroll
        for (int nt = 0; nt < 5; nt++) o[mt][nt][r] *= c;
        int prow = mt * 16 + lg * 4 + r;
        Pw[prow * 40 + lrow] = f2bf(p0);
        Pw[prow * 40 + 16 + lrow] = f2bf(p1);
      }
    }
    bf16x8 vf[5];
#pragma unroll
    for (int nt = 0; nt < 5; nt++)
      vf[nt] = *(const bf16x8*)&vh[(size_t)(nt * 16 + lrow) * SEQ + key0 + lg * 8];
    bf16x8 pa[2];
#pragma unroll
    for (int mt = 0; mt < 2; mt++)
      pa[mt] = *(const bf16x8*)&Pw[(mt * 16 + lrow) * 40 + lg * 8];
#pragma unroll
    for (int mt = 0; mt < 2; mt++)
#pragma unroll
      for (int nt = 0; nt < 5; nt++)
        o[mt][nt] = __builtin_amdgcn_mfma_f32_16x16x32_bf16(pa[mt], vf[nt], o[mt][nt], 0, 0, 0);
  }
#pragma unroll
  for (int mt = 0; mt < 2; mt++) {
#pragma unroll
    for (int r = 0; r < 4; r++) {
      float inv = 1.f / l_st[mt][r];
      int srow = qbase_s + mt * 16 + lg * 4 + r;
#pragma unroll
      for (int nt = 0; nt < 5; nt++)
        out[(size_t)srow * DIM + h * HD + nt * 16 + lrow] = f2bf(o[mt][nt][r] * inv);
    }
  }
}

extern "C" void kernel_launch(void* const* d_in, const int* in_sizes, int n_in,
                              void* d_out, int out_size, void* d_ws, size_t ws_size,
                              hipStream_t stream) {
  const float* hidden = (const float*)d_in[0];
  const float* cosb = (const float*)d_in[1];
  const float* sinb = (const float*)d_in[2];
  const float* qkv_w = (const float*)d_in[3];
  const float* qkv_b = (const float*)d_in[4];
  const float* proj_w = (const float*)d_in[5];
  const float* proj_b = (const float*)d_in[6];
  // cu_seqlens: fixed uniform segments (arange * 1024) — constants baked in.

  char* ws = (char*)d_ws;
  float* qkv_f = (float*)(ws);                     // 125,829,120 B (S x 3840 f32)
  short* attn_o = (short*)(ws);                    // alias (used after qkv dead): 20,971,520 B
  short* wp_bf = (short*)(ws + 23068672);          // alias in qkv region, cast after rope/vt
  short* q_bf = (short*)(ws + 125829120);          // (H,S,96) bf16
  short* k_bf = (short*)(ws + 150994944);          // (H,S,96) bf16
  short* v_tb = (short*)(ws + 176160768);          // (H,80,S) bf16
  short* h_bf = (short*)(ws + 197132288);          // (S,1280) bf16
  short* wq_bf = (short*)(ws + 218103808);         // (3840,1280) bf16  -> end 227,934,208

  cast_f32_bf16<<<4096, 256, 0, stream>>>(hidden, h_bf, SEQ * DIM);
  cast_f32_bf16<<<4096, 256, 0, stream>>>(qkv_w, wq_bf, 3 * DIM * DIM);
  gemm_bt_bias<<<dim3(30, 64), 256, 0, stream>>>(h_bf, wq_bf, qkv_b, qkv_f, SEQ, 3 * DIM, DIM);
  rope_qk<<<20480, 256, 0, stream>>>(qkv_f, cosb, sinb, q_bf, k_bf);
  v_transpose<<<dim3(128, 5, 16), 256, 0, stream>>>(qkv_f, v_tb);
  cast_f32_bf16<<<2048, 256, 0, stream>>>(proj_w, wp_bf, DIM * DIM);
  attn_kernel<<<1024, 256, 0, stream>>>(q_bf, k_bf, v_tb, attn_o);
  gemm_bt_bias<<<dim3(10, 64), 256, 0, stream>>>(attn_o, wp_bf, proj_b, (float*)d_out, SEQ, DIM, DIM);
}

// Round 3
// 379.821 us; speedup vs baseline: 1.1355x; 1.1355x over previous
//
#include <hip/hip_runtime.h>

#define SEQ 8192
#define DIM 1280
#define NHEADS 16
#define HD 80
#define HDP 96
#define NSEG 8
#define SEG 1024

typedef float f32x4 __attribute__((ext_vector_type(4)));
typedef short bf16x8 __attribute__((ext_vector_type(8)));

__device__ __forceinline__ float fast_exp2(float x) {
  return __builtin_amdgcn_exp2f(x);
}

__device__ __forceinline__ short f2bf(float f) {
  unsigned int u = __builtin_bit_cast(unsigned int, f);
  u = (u + 0x7fff + ((u >> 16) & 1)) >> 16;
  return (short)u;
}

typedef __attribute__((address_space(1))) const unsigned int glds_src_t;
typedef __attribute__((address_space(3))) unsigned int glds_dst_t;
__device__ __forceinline__ void gload_lds16(const void* g, void* l) {
  __builtin_amdgcn_global_load_lds((glds_src_t*)g, (glds_dst_t*)l, 16, 0, 0);
}

// ---------------- generic f32 -> bf16 cast (vectorized) ----------------
__global__ void cast_f32_bf16(const float* __restrict__ in, short* __restrict__ out, int n) {
  int n4 = n >> 2;
  for (int i = blockIdx.x * blockDim.x + threadIdx.x; i < n4; i += gridDim.x * blockDim.x) {
    float4 v = ((const float4*)in)[i];
    short4 o;
    o.x = f2bf(v.x); o.y = f2bf(v.y); o.z = f2bf(v.z); o.w = f2bf(v.w);
    ((short4*)out)[i] = o;
  }
}

// ---------------- bf16 GEMM, B^T layout (N,K), f32 out + bias ----------------
__global__ __launch_bounds__(256) void gemm_bt_bias(
    const short* __restrict__ A, const short* __restrict__ B,
    const float* __restrict__ bias, float* __restrict__ C,
    int M, int N, int K) {
  __shared__ short As[128 * 32];
  __shared__ short Bs[128 * 32];
  int tid = threadIdx.x;
  int w = tid >> 6, l = tid & 63;
  int lrow = l & 15, lg = l >> 4;
  int m0 = blockIdx.y * 128, n0 = blockIdx.x * 128;
  int wm = w & 1, wn = w >> 1;

  f32x4 acc[4][4] = {};

  const char* Abase = (const char*)A + (size_t)m0 * K * 2;
  const char* Bbase = (const char*)B + (size_t)n0 * K * 2;

  for (int k0 = 0; k0 < K; k0 += 32) {
#pragma unroll
    for (int j = 0; j < 2; j++) {
      int c = j * 256 + tid;
      int row = c >> 2;
      int kb = (c & 3) * 16;
      size_t goff = (size_t)row * K * 2 + (size_t)k0 * 2 + kb;
      int loff = (j * 256 + w * 64) * 16;
      gload_lds16(Abase + goff, (char*)As + loff);
      gload_lds16(Bbase + goff, (char*)Bs + loff);
    }
    __syncthreads();
    bf16x8 a[4], b[4];
#pragma unroll
    for (int mt = 0; mt < 4; mt++)
      a[mt] = *(const bf16x8*)&As[(wm * 64 + mt * 16 + lrow) * 32 + lg * 8];
#pragma unroll
    for (int nt = 0; nt < 4; nt++)
      b[nt] = *(const bf16x8*)&Bs[(wn * 64 + nt * 16 + lrow) * 32 + lg * 8];
#pragma unroll
    for (int mt = 0; mt < 4; mt++)
#pragma unroll
      for (int nt = 0; nt < 4; nt++)
        acc[mt][nt] = __builtin_amdgcn_mfma_f32_16x16x32_bf16(a[mt], b[nt], acc[mt][nt], 0, 0, 0);
    __syncthreads();
  }
#pragma unroll
  for (int nt = 0; nt < 4; nt++) {
    int col = n0 + wn * 64 + nt * 16 + lrow;
    float bv = bias[col];
#pragma unroll
    for (int mt = 0; mt < 4; mt++) {
      int mrow = m0 + wm * 64 + mt * 16 + lg * 4;
#pragma unroll
      for (int r = 0; r < 4; r++)
        C[(size_t)(mrow + r) * N + col] = acc[mt][nt][r] + bv;
    }
  }
}

// ---------------- RoPE for q,k (f32 in, bf16 out, head-major, pad to 96) ----------------
// q additionally scaled by 80^-0.5 * log2(e) (softmax done in exp2 domain).
__global__ void rope_qk(const float* __restrict__ qkv, const float* __restrict__ cosb,
                        const float* __restrict__ sinb, short* __restrict__ qg,
                        short* __restrict__ kg) {
  int t = blockIdx.x * blockDim.x + threadIdx.x;
  if (t >= SEQ * NHEADS * 40) return;
  int d = t % 40;
  int h = (t / 40) & 15;
  int s = t / 640;
  const float* row = qkv + (size_t)s * (3 * DIM);
  float c0 = cosb[s * HD + d], c1 = cosb[s * HD + d + 40];
  float s0 = sinb[s * HD + d], s1 = sinb[s * HD + d + 40];
  float x1 = row[h * HD + d], x2 = row[h * HD + d + 40];
  float q0 = x1 * c0 - x2 * s0;
  float q1 = x2 * c1 + x1 * s1;
  float y1 = row[DIM + h * HD + d], y2 = row[DIM + h * HD + d + 40];
  float k0 = y1 * c0 - y2 * s0;
  float k1 = y2 * c1 + y1 * s1;
  const float sc = 0.11180339887498949f * 1.4426950408889634f;
  size_t base = ((size_t)h * SEQ + s) * HDP;
  qg[base + d] = f2bf(q0 * sc);
  qg[base + d + 40] = f2bf(q1 * sc);
  kg[base + d] = f2bf(k0);
  kg[base + d + 40] = f2bf(k1);
  if (d < 16) { qg[base + 80 + d] = 0; kg[base + 80 + d] = 0; }
}

// ---------------- V transpose: qkv f32 (S,3,H,80) -> vt bf16 (H,80,S) ----------------
__global__ void v_transpose(const float* __restrict__ qkv, short* __restrict__ vt) {
  __shared__ float T[16][68];
  int st = blockIdx.x, dt = blockIdx.y, h = blockIdx.z;
  int d0 = dt * 16, s0 = st * 64;
  int t = threadIdx.x;
  int dd = t & 15, ss = t >> 4;
#pragma unroll
  for (int j = 0; j < 4; j++) {
    int s = ss + j * 16;
    T[dd][s] = qkv[(size_t)(s0 + s) * (3 * DIM) + 2 * DIM + h * HD + d0 + dd];
  }
  __syncthreads();
  int s2 = t & 63, dr = t >> 6;
#pragma unroll
  for (int j = 0; j < 4; j++) {
    int d = dr + j * 4;
    vt[((size_t)(h * HD + d0 + d)) * SEQ + s0 + s2] = f2bf(T[d][s2]);
  }
}

// ---------------- flash attention ----------------
// grid bid = qt*128 + h*8 + b  (XCD = bid%8 = b  -> all 8 q-tiles of one
// (h,seg) land on the same XCD L2). 4 waves x 32 q-rows, KV step 64.
// Swapped QK^T: mfma(K,Q) -> col=query, row=key. Lane owns one query's
// 16 keys in-register; reduce = in-lane tree + shfl_xor(16,32).
#define PST 72
__global__ __launch_bounds__(256) void attn_kernel(
    const short* __restrict__ qg, const short* __restrict__ kg,
    const short* __restrict__ vt, short* __restrict__ out) {
  __shared__ short Pl[4][32 * PST];
  int bid = blockIdx.x;
  int b = bid & 7, h = (bid >> 3) & 15, qt = bid >> 7;
  int w = threadIdx.x >> 6, l = threadIdx.x & 63;
  int lrow = l & 15, lg = l >> 4;
  int qbase_s = b * SEG + qt * 128 + w * 32;

  const short* qh = qg + (size_t)h * SEQ * HDP;
  const short* kh = kg + (size_t)h * SEQ * HDP;
  const short* vh = vt + (size_t)h * HD * SEQ;

  bf16x8 qf[2][3];
#pragma unroll
  for (int mt = 0; mt < 2; mt++)
#pragma unroll
    for (int ks = 0; ks < 3; ks++)
      qf[mt][ks] = *(const bf16x8*)&qh[(size_t)(qbase_s + mt * 16 + lrow) * HDP + ks * 32 + lg * 8];

  f32x4 o[2][5] = {};
  float m_st[2] = {-1e30f, -1e30f};
  float l_st[2] = {0.f, 0.f};

  short* Pw = &Pl[w][0];

  for (int kv = 0; kv < SEG; kv += 64) {
    int key0 = b * SEG + kv;
    f32x4 s[2][4] = {};
    {
      bf16x8 kf[4][3];
#pragma unroll
      for (int kt = 0; kt < 4; kt++)
#pragma unroll
        for (int ks = 0; ks < 3; ks++)
          kf[kt][ks] = *(const bf16x8*)&kh[(size_t)(key0 + kt * 16 + lrow) * HDP + ks * 32 + lg * 8];
#pragma unroll
      for (int kt = 0; kt < 4; kt++)
#pragma unroll
        for (int mt = 0; mt < 2; mt++)
#pragma unroll
          for (int ks = 0; ks < 3; ks++)
            s[mt][kt] = __builtin_amdgcn_mfma_f32_16x16x32_bf16(kf[kt][ks], qf[mt][ks], s[mt][kt], 0, 0, 0);
    }
    // per-query tile max: in-lane over 16, then 2 shfl
    float cm[2];
#pragma unroll
    for (int mt = 0; mt < 2; mt++) {
      float a0 = fmaxf(fmaxf(s[mt][0][0], s[mt][0][1]), fmaxf(s[mt][0][2], s[mt][0][3]));
      float a1 = fmaxf(fmaxf(s[mt][1][0], s[mt][1][1]), fmaxf(s[mt][1][2], s[mt][1][3]));
      float a2 = fmaxf(fmaxf(s[mt][2][0], s[mt][2][1]), fmaxf(s[mt][2][2], s[mt][2][3]));
      float a3 = fmaxf(fmaxf(s[mt][3][0], s[mt][3][1]), fmaxf(s[mt][3][2], s[mt][3][3]));
      float c = fmaxf(fmaxf(a0, a1), fmaxf(a2, a3));
      c = fmaxf(c, __shfl_xor(c, 16));
      c = fmaxf(c, __shfl_xor(c, 32));
      cm[mt] = c;
    }
    // defer-max: only rescale when a query's max grew by > 8 (log2 units)
    if (__any((cm[0] > m_st[0] + 8.f) || (cm[1] > m_st[1] + 8.f))) {
#pragma unroll
      for (int mt = 0; mt < 2; mt++) {
        float mn = fmaxf(m_st[mt], cm[mt]);
        float c = fast_exp2(m_st[mt] - mn);
        m_st[mt] = mn;
        l_st[mt] *= c;
        float cr[4];
#pragma unroll
        for (int r = 0; r < 4; r++) cr[r] = __shfl(c, lg * 4 + r);
#pragma unroll
        for (int nt = 0; nt < 5; nt++)
#pragma unroll
          for (int r = 0; r < 4; r++) o[mt][nt][r] *= cr[r];
      }
    }
    // p = exp2(s - m); accumulate l; pack 4 keys -> one b64 LDS write
#pragma unroll
    for (int mt = 0; mt < 2; mt++) {
      float rs = 0.f;
#pragma unroll
      for (int kt = 0; kt < 4; kt++) {
#pragma unroll
        for (int r = 0; r < 4; r++) {
          s[mt][kt][r] = fast_exp2(s[mt][kt][r] - m_st[mt]);
          rs += s[mt][kt][r];
        }
        short4 pk;
        pk.x = f2bf(s[mt][kt][0]); pk.y = f2bf(s[mt][kt][1]);
        pk.z = f2bf(s[mt][kt][2]); pk.w = f2bf(s[mt][kt][3]);
        *(short4*)&Pw[(mt * 16 + lrow) * PST + kt * 16 + lg * 4] = pk;
      }
      rs += __shfl_xor(rs, 16);
      rs += __shfl_xor(rs, 32);
      l_st[mt] += rs;
    }
    // PV
    bf16x8 vf[5][2];
#pragma unroll
    for (int nt = 0; nt < 5; nt++)
#pragma unroll
      for (int ks = 0; ks < 2; ks++)
        vf[nt][ks] = *(const bf16x8*)&vh[(size_t)(nt * 16 + lrow) * SEQ + key0 + ks * 32 + lg * 8];
    bf16x8 pa[2][2];
#pragma unroll
    for (int mt = 0; mt < 2; mt++)
#pragma unroll
      for (int ks = 0; ks < 2; ks++)
        pa[mt][ks] = *(const bf16x8*)&Pw[(mt * 16 + lrow) * PST + ks * 32 + lg * 8];
#pragma unroll
    for (int mt = 0; mt < 2; mt++)
#pragma unroll
      for (int nt = 0; nt < 5; nt++)
#pragma unroll
        for (int ks = 0; ks < 2; ks++)
          o[mt][nt] = __builtin_amdgcn_mfma_f32_16x16x32_bf16(pa[mt][ks], vf[nt][ks], o[mt][nt], 0, 0, 0);
  }
#pragma unroll
  for (int mt = 0; mt < 2; mt++) {
    float rl = 1.f / l_st[mt];
    float ir[4];
#pragma unroll
    for (int r = 0; r < 4; r++) ir[r] = __shfl(rl, lg * 4 + r);
#pragma unroll
    for (int r = 0; r < 4; r++) {
      int srow = qbase_s + mt * 16 + lg * 4 + r;
#pragma unroll
      for (int nt = 0; nt < 5; nt++)
        out[(size_t)srow * DIM + h * HD + nt * 16 + lrow] = f2bf(o[mt][nt][r] * ir[r]);
    }
  }
}

extern "C" void kernel_launch(void* const* d_in, const int* in_sizes, int n_in,
                              void* d_out, int out_size, void* d_ws, size_t ws_size,
                              hipStream_t stream) {
  const float* hidden = (const float*)d_in[0];
  const float* cosb = (const float*)d_in[1];
  const float* sinb = (const float*)d_in[2];
  const float* qkv_w = (const float*)d_in[3];
  const float* qkv_b = (const float*)d_in[4];
  const float* proj_w = (const float*)d_in[5];
  const float* proj_b = (const float*)d_in[6];

  char* ws = (char*)d_ws;
  float* qkv_f = (float*)(ws);
  short* attn_o = (short*)(ws);
  short* wp_bf = (short*)(ws + 23068672);
  short* q_bf = (short*)(ws + 125829120);
  short* k_bf = (short*)(ws + 150994944);
  short* v_tb = (short*)(ws + 176160768);
  short* h_bf = (short*)(ws + 197132288);
  short* wq_bf = (short*)(ws + 218103808);

  cast_f32_bf16<<<4096, 256, 0, stream>>>(hidden, h_bf, SEQ * DIM);
  cast_f32_bf16<<<4096, 256, 0, stream>>>(qkv_w, wq_bf, 3 * DIM * DIM);
  gemm_bt_bias<<<dim3(30, 64), 256, 0, stream>>>(h_bf, wq_bf, qkv_b, qkv_f, SEQ, 3 * DIM, DIM);
  rope_qk<<<20480, 256, 0, stream>>>(qkv_f, cosb, sinb, q_bf, k_bf);
  v_transpose<<<dim3(128, 5, 16), 256, 0, stream>>>(qkv_f, v_tb);
  cast_f32_bf16<<<2048, 256, 0, stream>>>(proj_w, wp_bf, DIM * DIM);
  attn_kernel<<<1024, 256, 0, stream>>>(q_bf, k_bf, v_tb, attn_o);
  gemm_bt_bias<<<dim3(10, 64), 256, 0, stream>>>(attn_o, wp_bf, proj_b, (float*)d_out, SEQ, DIM, DIM);
}

// Round 5
// 364.026 us; speedup vs baseline: 1.1847x; 1.0434x over previous
//
#include <hip/hip_runtime.h>

#define SEQ 8192
#define DIM 1280
#define NHEADS 16
#define HD 80
#define HDP 96
#define NSEG 8
#define SEG 1024

typedef float f32x4 __attribute__((ext_vector_type(4)));
typedef short bf16x8 __attribute__((ext_vector_type(8)));

__device__ __forceinline__ float fast_exp2(float x) {
  return __builtin_amdgcn_exp2f(x);
}

__device__ __forceinline__ short f2bf(float f) {
  unsigned int u = __builtin_bit_cast(unsigned int, f);
  u = (u + 0x7fff + ((u >> 16) & 1)) >> 16;
  return (short)u;
}

typedef __attribute__((address_space(1))) const unsigned int glds_src_t;
typedef __attribute__((address_space(3))) unsigned int glds_dst_t;
__device__ __forceinline__ void gload_lds16(const void* g, void* l) {
  __builtin_amdgcn_global_load_lds((glds_src_t*)g, (glds_dst_t*)l, 16, 0, 0);
}

// ---------------- generic f32 -> bf16 cast (vectorized) ----------------
__global__ void cast_f32_bf16(const float* __restrict__ in, short* __restrict__ out, int n) {
  int n4 = n >> 2;
  for (int i = blockIdx.x * blockDim.x + threadIdx.x; i < n4; i += gridDim.x * blockDim.x) {
    float4 v = ((const float4*)in)[i];
    short4 o;
    o.x = f2bf(v.x); o.y = f2bf(v.y); o.z = f2bf(v.z); o.w = f2bf(v.w);
    ((short4*)out)[i] = o;
  }
}

// ---------------- bf16 GEMM, B^T layout (N,K), f32 out + bias ----------------
__global__ __launch_bounds__(256) void gemm_bt_bias(
    const short* __restrict__ A, const short* __restrict__ B,
    const float* __restrict__ bias, float* __restrict__ C,
    int M, int N, int K) {
  __shared__ short As[128 * 32];
  __shared__ short Bs[128 * 32];
  int tid = threadIdx.x;
  int w = tid >> 6, l = tid & 63;
  int lrow = l & 15, lg = l >> 4;
  int m0 = blockIdx.y * 128, n0 = blockIdx.x * 128;
  int wm = w & 1, wn = w >> 1;

  f32x4 acc[4][4] = {};

  const char* Abase = (const char*)A + (size_t)m0 * K * 2;
  const char* Bbase = (const char*)B + (size_t)n0 * K * 2;

  for (int k0 = 0; k0 < K; k0 += 32) {
#pragma unroll
    for (int j = 0; j < 2; j++) {
      int c = j * 256 + tid;
      int row = c >> 2;
      int kb = (c & 3) * 16;
      size_t goff = (size_t)row * K * 2 + (size_t)k0 * 2 + kb;
      int loff = (j * 256 + w * 64) * 16;
      gload_lds16(Abase + goff, (char*)As + loff);
      gload_lds16(Bbase + goff, (char*)Bs + loff);
    }
    __syncthreads();
    bf16x8 a[4], b[4];
#pragma unroll
    for (int mt = 0; mt < 4; mt++)
      a[mt] = *(const bf16x8*)&As[(wm * 64 + mt * 16 + lrow) * 32 + lg * 8];
#pragma unroll
    for (int nt = 0; nt < 4; nt++)
      b[nt] = *(const bf16x8*)&Bs[(wn * 64 + nt * 16 + lrow) * 32 + lg * 8];
#pragma unroll
    for (int mt = 0; mt < 4; mt++)
#pragma unroll
      for (int nt = 0; nt < 4; nt++)
        acc[mt][nt] = __builtin_amdgcn_mfma_f32_16x16x32_bf16(a[mt], b[nt], acc[mt][nt], 0, 0, 0);
    __syncthreads();
  }
#pragma unroll
  for (int nt = 0; nt < 4; nt++) {
    int col = n0 + wn * 64 + nt * 16 + lrow;
    float bv = bias[col];
#pragma unroll
    for (int mt = 0; mt < 4; mt++) {
      int mrow = m0 + wm * 64 + mt * 16 + lg * 4;
#pragma unroll
      for (int r = 0; r < 4; r++)
        C[(size_t)(mrow + r) * N + col] = acc[mt][nt][r] + bv;
    }
  }
}

// ---------------- RoPE for q,k (f32 in, bf16 out, head-major, pad to 96) ----------------
// q additionally scaled by 80^-0.5 * log2(e) (softmax done in exp2 domain).
__global__ void rope_qk(const float* __restrict__ qkv, const float* __restrict__ cosb,
                        const float* __restrict__ sinb, short* __restrict__ qg,
                        short* __restrict__ kg) {
  int t = blockIdx.x * blockDim.x + threadIdx.x;
  if (t >= SEQ * NHEADS * 40) return;
  int d = t % 40;
  int h = (t / 40) & 15;
  int s = t / 640;
  const float* row = qkv + (size_t)s * (3 * DIM);
  float c0 = cosb[s * HD + d], c1 = cosb[s * HD + d + 40];
  float s0 = sinb[s * HD + d], s1 = sinb[s * HD + d + 40];
  float x1 = row[h * HD + d], x2 = row[h * HD + d + 40];
  float q0 = x1 * c0 - x2 * s0;
  float q1 = x2 * c1 + x1 * s1;
  float y1 = row[DIM + h * HD + d], y2 = row[DIM + h * HD + d + 40];
  float k0 = y1 * c0 - y2 * s0;
  float k1 = y2 * c1 + y1 * s1;
  const float sc = 0.11180339887498949f * 1.4426950408889634f;
  size_t base = ((size_t)h * SEQ + s) * HDP;
  qg[base + d] = f2bf(q0 * sc);
  qg[base + d + 40] = f2bf(q1 * sc);
  kg[base + d] = f2bf(k0);
  kg[base + d + 40] = f2bf(k1);
  if (d < 16) { qg[base + 80 + d] = 0; kg[base + 80 + d] = 0; }
}

// ---------------- V transpose: qkv f32 (S,3,H,80) -> vt bf16 (H,80,S) ----------------
__global__ void v_transpose(const float* __restrict__ qkv, short* __restrict__ vt) {
  __shared__ float T[16][68];
  int st = blockIdx.x, dt = blockIdx.y, h = blockIdx.z;
  int d0 = dt * 16, s0 = st * 64;
  int t = threadIdx.x;
  int dd = t & 15, ss = t >> 4;
#pragma unroll
  for (int j = 0; j < 4; j++) {
    int s = ss + j * 16;
    T[dd][s] = qkv[(size_t)(s0 + s) * (3 * DIM) + 2 * DIM + h * HD + d0 + dd];
  }
  __syncthreads();
  int s2 = t & 63, dr = t >> 6;
#pragma unroll
  for (int j = 0; j < 4; j++) {
    int d = dr + j * 4;
    vt[((size_t)(h * HD + d0 + d)) * SEQ + s0 + s2] = f2bf(T[d][s2]);
  }
}

// ---------------- flash attention ----------------
// grid bid = qt*128 + h*8 + b  (XCD = bid%8 = b). 4 waves x 32 q-rows,
// KV step 64, 2x unrolled with register double-buffered K prefetch
// (kfA/kfB) and early V issue (T14 issue-early/use-late).
// NOTE: macro locals are suffixed (lk_key, kb0) to avoid shadowing the
// caller's variables passed as arguments (round-4 bug).
#define PST 72
__global__ __launch_bounds__(256, 2) void attn_kernel(
    const short* __restrict__ qg, const short* __restrict__ kg,
    const short* __restrict__ vt, short* __restrict__ out) {
  __shared__ short Pl[4][32 * PST];
  int bid = blockIdx.x;
  int b = bid & 7, h = (bid >> 3) & 15, qt = bid >> 7;
  int w = threadIdx.x >> 6, l = threadIdx.x & 63;
  int lrow = l & 15, lg = l >> 4;
  int qbase_s = b * SEG + qt * 128 + w * 32;

  const short* qh = qg + (size_t)h * SEQ * HDP;
  const short* kh = kg + (size_t)h * SEQ * HDP;
  const short* vh = vt + (size_t)h * HD * SEQ;

  bf16x8 qf[2][3];
#pragma unroll
  for (int mt = 0; mt < 2; mt++)
#pragma unroll
    for (int ks = 0; ks < 3; ks++)
      qf[mt][ks] = *(const bf16x8*)&qh[(size_t)(qbase_s + mt * 16 + lrow) * HDP + ks * 32 + lg * 8];

  f32x4 o[2][5] = {};
  float m_st[2] = {-1e30f, -1e30f};
  float l_st[2] = {0.f, 0.f};

  short* Pw = &Pl[w][0];

  bf16x8 kfA[4][3], kfB[4][3];

#define LOAD_KF(DST, KEY)                                                     \
  {                                                                           \
    int lk_key = (KEY);                                                       \
    _Pragma("unroll") for (int kt = 0; kt < 4; kt++)                          \
        _Pragma("unroll") for (int ks = 0; ks < 3; ks++)                      \
            DST[kt][ks] = *(const bf16x8*)&kh[(size_t)(lk_key + kt * 16 + lrow) * HDP + ks * 32 + lg * 8]; \
  }

#define ATTN_PHASE(KF, KEY, PRE, PRE_KEY)                                     \
  {                                                                           \
    int kb0 = (KEY);                                                          \
    /* issue V loads for current tile first (latency hidden by QK+softmax) */ \
    bf16x8 vf[5][2];                                                          \
    _Pragma("unroll") for (int nt = 0; nt < 5; nt++)                          \
        _Pragma("unroll") for (int ks = 0; ks < 2; ks++)                      \
            vf[nt][ks] = *(const bf16x8*)&vh[(size_t)(nt * 16 + lrow) * SEQ + kb0 + ks * 32 + lg * 8]; \
    /* prefetch next K tile into the alternate register buffer */             \
    LOAD_KF(PRE, PRE_KEY);                                                    \
    f32x4 s[2][4] = {};                                                       \
    _Pragma("unroll") for (int kt = 0; kt < 4; kt++)                          \
        _Pragma("unroll") for (int mt = 0; mt < 2; mt++)                      \
            _Pragma("unroll") for (int ks = 0; ks < 3; ks++)                  \
                s[mt][kt] = __builtin_amdgcn_mfma_f32_16x16x32_bf16(KF[kt][ks], qf[mt][ks], s[mt][kt], 0, 0, 0); \
    float cm[2];                                                              \
    _Pragma("unroll") for (int mt = 0; mt < 2; mt++) {                        \
      float a0 = fmaxf(fmaxf(s[mt][0][0], s[mt][0][1]), fmaxf(s[mt][0][2], s[mt][0][3])); \
      float a1 = fmaxf(fmaxf(s[mt][1][0], s[mt][1][1]), fmaxf(s[mt][1][2], s[mt][1][3])); \
      float a2 = fmaxf(fmaxf(s[mt][2][0], s[mt][2][1]), fmaxf(s[mt][2][2], s[mt][2][3])); \
      float a3 = fmaxf(fmaxf(s[mt][3][0], s[mt][3][1]), fmaxf(s[mt][3][2], s[mt][3][3])); \
      float c = fmaxf(fmaxf(a0, a1), fmaxf(a2, a3));                          \
      c = fmaxf(c, __shfl_xor(c, 16));                                        \
      c = fmaxf(c, __shfl_xor(c, 32));                                        \
      cm[mt] = c;                                                             \
    }                                                                         \
    if (__any((cm[0] > m_st[0] + 8.f) || (cm[1] > m_st[1] + 8.f))) {          \
      _Pragma("unroll") for (int mt = 0; mt < 2; mt++) {                      \
        float mn = fmaxf(m_st[mt], cm[mt]);                                   \
        float c = fast_exp2(m_st[mt] - mn);                                   \
        m_st[mt] = mn;                                                        \
        l_st[mt] *= c;                                                        \
        float cr[4];                                                          \
        _Pragma("unroll") for (int r = 0; r < 4; r++) cr[r] = __shfl(c, lg * 4 + r); \
        _Pragma("unroll") for (int nt = 0; nt < 5; nt++)                      \
            _Pragma("unroll") for (int r = 0; r < 4; r++) o[mt][nt][r] *= cr[r]; \
      }                                                                       \
    }                                                                         \
    _Pragma("unroll") for (int mt = 0; mt < 2; mt++) {                        \
      float rs = 0.f;                                                         \
      _Pragma("unroll") for (int kt = 0; kt < 4; kt++) {                      \
        _Pragma("unroll") for (int r = 0; r < 4; r++) {                       \
          s[mt][kt][r] = fast_exp2(s[mt][kt][r] - m_st[mt]);                  \
          rs += s[mt][kt][r];                                                 \
        }                                                                     \
        short4 pk;                                                            \
        pk.x = f2bf(s[mt][kt][0]); pk.y = f2bf(s[mt][kt][1]);                 \
        pk.z = f2bf(s[mt][kt][2]); pk.w = f2bf(s[mt][kt][3]);                 \
        *(short4*)&Pw[(mt * 16 + lrow) * PST + kt * 16 + lg * 4] = pk;        \
      }                                                                       \
      rs += __shfl_xor(rs, 16);                                               \
      rs += __shfl_xor(rs, 32);                                               \
      l_st[mt] += rs;                                                         \
    }                                                                         \
    bf16x8 pa[2][2];                                                          \
    _Pragma("unroll") for (int mt = 0; mt < 2; mt++)                          \
        _Pragma("unroll") for (int ks = 0; ks < 2; ks++)                      \
            pa[mt][ks] = *(const bf16x8*)&Pw[(mt * 16 + lrow) * PST + ks * 32 + lg * 8]; \
    _Pragma("unroll") for (int mt = 0; mt < 2; mt++)                          \
        _Pragma("unroll") for (int nt = 0; nt < 5; nt++)                      \
            _Pragma("unroll") for (int ks = 0; ks < 2; ks++)                  \
                o[mt][nt] = __builtin_amdgcn_mfma_f32_16x16x32_bf16(pa[mt][ks], vf[nt][ks], o[mt][nt], 0, 0, 0); \
  }

  LOAD_KF(kfA, b * SEG);
  for (int kv = 0; kv < SEG; kv += 128) {
    int key0 = b * SEG + kv;
    ATTN_PHASE(kfA, key0, kfB, key0 + 64);
    // last prefetch (key0+192 at kv=SEG-128) reads 12KB past this head's K —
    // lands in adjacent ws buffers, never used. Safe.
    ATTN_PHASE(kfB, key0 + 64, kfA, key0 + 128);
  }

#pragma unroll
  for (int mt = 0; mt < 2; mt++) {
    float rl = 1.f / l_st[mt];
    float ir[4];
#pragma unroll
    for (int r = 0; r < 4; r++) ir[r] = __shfl(rl, lg * 4 + r);
#pragma unroll
    for (int r = 0; r < 4; r++) {
      int srow = qbase_s + mt * 16 + lg * 4 + r;
#pragma unroll
      for (int nt = 0; nt < 5; nt++)
        out[(size_t)srow * DIM + h * HD + nt * 16 + lrow] = f2bf(o[mt][nt][r] * ir[r]);
    }
  }
}

extern "C" void kernel_launch(void* const* d_in, const int* in_sizes, int n_in,
                              void* d_out, int out_size, void* d_ws, size_t ws_size,
                              hipStream_t stream) {
  const float* hidden = (const float*)d_in[0];
  const float* cosb = (const float*)d_in[1];
  const float* sinb = (const float*)d_in[2];
  const float* qkv_w = (const float*)d_in[3];
  const float* qkv_b = (const float*)d_in[4];
  const float* proj_w = (const float*)d_in[5];
  const float* proj_b = (const float*)d_in[6];

  char* ws = (char*)d_ws;
  float* qkv_f = (float*)(ws);
  short* attn_o = (short*)(ws);
  short* wp_bf = (short*)(ws + 23068672);
  short* q_bf = (short*)(ws + 125829120);
  short* k_bf = (short*)(ws + 150994944);
  short* v_tb = (short*)(ws + 176160768);
  short* h_bf = (short*)(ws + 197132288);
  short* wq_bf = (short*)(ws + 218103808);

  cast_f32_bf16<<<4096, 256, 0, stream>>>(hidden, h_bf, SEQ * DIM);
  cast_f32_bf16<<<4096, 256, 0, stream>>>(qkv_w, wq_bf, 3 * DIM * DIM);
  gemm_bt_bias<<<dim3(30, 64), 256, 0, stream>>>(h_bf, wq_bf, qkv_b, qkv_f, SEQ, 3 * DIM, DIM);
  rope_qk<<<20480, 256, 0, stream>>>(qkv_f, cosb, sinb, q_bf, k_bf);
  v_transpose<<<dim3(128, 5, 16), 256, 0, stream>>>(qkv_f, v_tb);
  cast_f32_bf16<<<2048, 256, 0, stream>>>(proj_w, wp_bf, DIM * DIM);
  attn_kernel<<<1024, 256, 0, stream>>>(q_bf, k_bf, v_tb, attn_o);
  gemm_bt_bias<<<dim3(10, 64), 256, 0, stream>>>(attn_o, wp_bf, proj_b, (float*)d_out, SEQ, DIM, DIM);
}

// Round 8
// 359.674 us; speedup vs baseline: 1.1991x; 1.0121x over previous
//
#include <hip/hip_runtime.h>

#define SEQ 8192
#define DIM 1280
#define NHEADS 16
#define HD 80
#define HDP 96
#define NSEG 8
#define SEG 1024
#define KVB 64
#define NSTEP (SEG / KVB)
#define PST 72

typedef float f32x4 __attribute__((ext_vector_type(4)));
typedef short bf16x8 __attribute__((ext_vector_type(8)));
typedef unsigned int u32;

__device__ __forceinline__ float fast_exp2(float x) {
  return __builtin_amdgcn_exp2f(x);
}

__device__ __forceinline__ short f2bf(float f) {
  unsigned int u = __builtin_bit_cast(unsigned int, f);
  u = (u + 0x7fff + ((u >> 16) & 1)) >> 16;
  return (short)u;
}

typedef __attribute__((address_space(1))) const unsigned int glds_src_t;
typedef __attribute__((address_space(3))) unsigned int glds_dst_t;
__device__ __forceinline__ void gload_lds16(const void* g, void* l) {
  __builtin_amdgcn_global_load_lds((glds_src_t*)g, (glds_dst_t*)l, 16, 0, 0);
}

// ---------------- generic f32 -> bf16 cast (vectorized) ----------------
__global__ void cast_f32_bf16(const float* __restrict__ in, short* __restrict__ out, int n) {
  int n4 = n >> 2;
  for (int i = blockIdx.x * blockDim.x + threadIdx.x; i < n4; i += gridDim.x * blockDim.x) {
    float4 v = ((const float4*)in)[i];
    short4 o;
    o.x = f2bf(v.x); o.y = f2bf(v.y); o.z = f2bf(v.z); o.w = f2bf(v.w);
    ((short4*)out)[i] = o;
  }
}

// ---------------- bf16 GEMM, B^T layout (N,K), f32 out + bias ----------------
__global__ __launch_bounds__(256) void gemm_bt_bias(
    const short* __restrict__ A, const short* __restrict__ B,
    const float* __restrict__ bias, float* __restrict__ C,
    int M, int N, int K) {
  __shared__ short As[128 * 32];
  __shared__ short Bs[128 * 32];
  int tid = threadIdx.x;
  int w = tid >> 6, l = tid & 63;
  int lrow = l & 15, lg = l >> 4;
  int m0 = blockIdx.y * 128, n0 = blockIdx.x * 128;
  int wm = w & 1, wn = w >> 1;

  f32x4 acc[4][4] = {};

  const char* Abase = (const char*)A + (size_t)m0 * K * 2;
  const char* Bbase = (const char*)B + (size_t)n0 * K * 2;

  for (int k0 = 0; k0 < K; k0 += 32) {
#pragma unroll
    for (int j = 0; j < 2; j++) {
      int c = j * 256 + tid;
      int row = c >> 2;
      int kb = (c & 3) * 16;
      size_t goff = (size_t)row * K * 2 + (size_t)k0 * 2 + kb;
      int loff = (j * 256 + w * 64) * 16;
      gload_lds16(Abase + goff, (char*)As + loff);
      gload_lds16(Bbase + goff, (char*)Bs + loff);
    }
    __syncthreads();
    bf16x8 a[4], b[4];
#pragma unroll
    for (int mt = 0; mt < 4; mt++)
      a[mt] = *(const bf16x8*)&As[(wm * 64 + mt * 16 + lrow) * 32 + lg * 8];
#pragma unroll
    for (int nt = 0; nt < 4; nt++)
      b[nt] = *(const bf16x8*)&Bs[(wn * 64 + nt * 16 + lrow) * 32 + lg * 8];
#pragma unroll
    for (int mt = 0; mt < 4; mt++)
#pragma unroll
      for (int nt = 0; nt < 4; nt++)
        acc[mt][nt] = __builtin_amdgcn_mfma_f32_16x16x32_bf16(a[mt], b[nt], acc[mt][nt], 0, 0, 0);
    __syncthreads();
  }
#pragma unroll
  for (int nt = 0; nt < 4; nt++) {
    int col = n0 + wn * 64 + nt * 16 + lrow;
    float bv = bias[col];
#pragma unroll
    for (int mt = 0; mt < 4; mt++) {
      int mrow = m0 + wm * 64 + mt * 16 + lg * 4;
#pragma unroll
      for (int r = 0; r < 4; r++)
        C[(size_t)(mrow + r) * N + col] = acc[mt][nt][r] + bv;
    }
  }
}

// ---------------- RoPE for q,k (f32 in, bf16 out, head-major, pad to 96) ----------------
// q additionally scaled by 80^-0.5 * log2(e) (softmax done in exp2 domain).
__global__ void rope_qk(const float* __restrict__ qkv, const float* __restrict__ cosb,
                        const float* __restrict__ sinb, short* __restrict__ qg,
                        short* __restrict__ kg) {
  int t = blockIdx.x * blockDim.x + threadIdx.x;
  if (t >= SEQ * NHEADS * 40) return;
  int d = t % 40;
  int h = (t / 40) & 15;
  int s = t / 640;
  const float* row = qkv + (size_t)s * (3 * DIM);
  float c0 = cosb[s * HD + d], c1 = cosb[s * HD + d + 40];
  float s0 = sinb[s * HD + d], s1 = sinb[s * HD + d + 40];
  float x1 = row[h * HD + d], x2 = row[h * HD + d + 40];
  float q0 = x1 * c0 - x2 * s0;
  float q1 = x2 * c1 + x1 * s1;
  float y1 = row[DIM + h * HD + d], y2 = row[DIM + h * HD + d + 40];
  float k0 = y1 * c0 - y2 * s0;
  float k1 = y2 * c1 + y1 * s1;
  const float sc = 0.11180339887498949f * 1.4426950408889634f;
  size_t base = ((size_t)h * SEQ + s) * HDP;
  qg[base + d] = f2bf(q0 * sc);
  qg[base + d + 40] = f2bf(q1 * sc);
  kg[base + d] = f2bf(k0);
  kg[base + d + 40] = f2bf(k1);
  if (d < 16) { qg[base + 80 + d] = 0; kg[base + 80 + d] = 0; }
}

// ---------------- V transpose: qkv f32 (S,3,H,80) -> vt bf16 (H,80,S) ----------------
__global__ void v_transpose(const float* __restrict__ qkv, short* __restrict__ vt) {
  __shared__ float T[16][68];
  int st = blockIdx.x, dt = blockIdx.y, h = blockIdx.z;
  int d0 = dt * 16, s0 = st * 64;
  int t = threadIdx.x;
  int dd = t & 15, ss = t >> 4;
#pragma unroll
  for (int j = 0; j < 4; j++) {
    int s = ss + j * 16;
    T[dd][s] = qkv[(size_t)(s0 + s) * (3 * DIM) + 2 * DIM + h * HD + d0 + dd];
  }
  __syncthreads();
  int s2 = t & 63, dr = t >> 6;
#pragma unroll
  for (int j = 0; j < 4; j++) {
    int d = dr + j * 4;
    vt[((size_t)(h * HD + d0 + d)) * SEQ + s0 + s2] = f2bf(T[d][s2]);
  }
}

// ---------------- flash attention v4 (bisect: K-LDS only) ----------------
// grid 512, 512 threads (8 waves x 32 q-rows). K double-buffered in LDS,
// staged cooperatively via global_load_lds (linear LDS dest + XOR-swizzled
// global source; read applies the same XOR — rule #21 involution). V read
// directly from global (round-5 proven path). P via f2bf (round-5 proven).
// One barrier per iteration (at end): drains stage vmcnt before next QK
// and orders buffer reuse.
__global__ __launch_bounds__(512, 4) void attn_kernel(
    const short* __restrict__ qg, const short* __restrict__ kg,
    const short* __restrict__ vt, short* __restrict__ out) {
  __shared__ short Ks[2][64 * 128];  // 32 KB (rows padded 96->128 shorts)
  __shared__ short Pl[8][32 * PST];  // 36 KB
  int bid = blockIdx.x;
  int b = bid & 7, h = (bid >> 3) & 15, qt = bid >> 7;
  int tid = threadIdx.x;
  int w = tid >> 6, l = tid & 63;
  int lrow = l & 15, lg = l >> 4;
  int qbase_s = b * SEG + qt * 256 + w * 32;

  const short* qh = qg + (size_t)h * SEQ * HDP;
  const short* kh = kg + (size_t)h * SEQ * HDP;
  const short* vh = vt + (size_t)h * HD * SEQ;

  // K stage: 1024 slots x 16B, 2 rounds of 512 threads. LDS dest is
  // wave-uniform base (HW adds lane*16); global src carries the swizzle:
  // physical chunk sc of row skey holds logical chunk sc^(skey&7).
#define STAGE_K(BUF, KEY0N)                                                    \
  {                                                                            \
    _Pragma("unroll") for (int sr = 0; sr < 2; sr++) {                         \
      int sbase = sr * 512 + w * 64;                                           \
      int ss = sbase + l;                                                      \
      int skey = ss >> 4, sc = ss & 15;                                        \
      int slc = sc ^ (skey & 7);                                               \
      const short* ssrc =                                                      \
          kh + (size_t)((KEY0N) + skey) * HDP + (slc < 12 ? slc * 8 : 0);      \
      gload_lds16(ssrc, (char*)&Ks[BUF][0] + sbase * 16);                      \
    }                                                                          \
  }

  bf16x8 qf[2][3];
#pragma unroll
  for (int mt = 0; mt < 2; mt++)
#pragma unroll
    for (int ks = 0; ks < 3; ks++)
      qf[mt][ks] = *(const bf16x8*)&qh[(size_t)(qbase_s + mt * 16 + lrow) * HDP + ks * 32 + lg * 8];

  f32x4 o[2][5] = {};
  float m_st[2] = {-1e30f, -1e30f};
  float l_st[2] = {0.f, 0.f};

  short* Pw = &Pl[w][0];

  STAGE_K(0, b * SEG);
  __syncthreads();

  for (int i = 0; i < NSTEP; i++) {
    int cur = i & 1;
    int key0 = b * SEG + i * KVB;
    if (i + 1 < NSTEP) {
      STAGE_K(cur ^ 1, key0 + KVB);
    }

    // --- QK^T (swapped: mfma(K,Q), col=query, key in-lane) from LDS ---
    f32x4 sv[2][4] = {};
#pragma unroll
    for (int kt = 0; kt < 4; kt++) {
      bf16x8 kf[3];
      int key = kt * 16 + lrow;
#pragma unroll
      for (int ks = 0; ks < 3; ks++) {
        int p = (ks * 4 + lg) ^ (key & 7);
        kf[ks] = *(const bf16x8*)&Ks[cur][key * 128 + p * 8];
      }
#pragma unroll
      for (int mt = 0; mt < 2; mt++)
#pragma unroll
        for (int ks = 0; ks < 3; ks++)
          sv[mt][kt] = __builtin_amdgcn_mfma_f32_16x16x32_bf16(kf[ks], qf[mt][ks], sv[mt][kt], 0, 0, 0);
    }

    // --- per-query tile max: in-lane over 16 keys, then 2 shfl ---
    float cm[2];
#pragma unroll
    for (int mt = 0; mt < 2; mt++) {
      float a0 = fmaxf(fmaxf(sv[mt][0][0], sv[mt][0][1]), fmaxf(sv[mt][0][2], sv[mt][0][3]));
      float a1 = fmaxf(fmaxf(sv[mt][1][0], sv[mt][1][1]), fmaxf(sv[mt][1][2], sv[mt][1][3]));
      float a2 = fmaxf(fmaxf(sv[mt][2][0], sv[mt][2][1]), fmaxf(sv[mt][2][2], sv[mt][2][3]));
      float a3 = fmaxf(fmaxf(sv[mt][3][0], sv[mt][3][1]), fmaxf(sv[mt][3][2], sv[mt][3][3]));
      float c = fmaxf(fmaxf(a0, a1), fmaxf(a2, a3));
      c = fmaxf(c, __shfl_xor(c, 16));
      c = fmaxf(c, __shfl_xor(c, 32));
      cm[mt] = c;
    }
    // defer-max: rescale only when max grew by > 8 (log2 units)
    if (__any((cm[0] > m_st[0] + 8.f) || (cm[1] > m_st[1] + 8.f))) {
#pragma unroll
      for (int mt = 0; mt < 2; mt++) {
        float mn = fmaxf(m_st[mt], cm[mt]);
        float c = fast_exp2(m_st[mt] - mn);
        m_st[mt] = mn;
        l_st[mt] *= c;
        float cr[4];
#pragma unroll
        for (int r = 0; r < 4; r++) cr[r] = __shfl(c, lg * 4 + r);
#pragma unroll
        for (int nt = 0; nt < 5; nt++)
#pragma unroll
          for (int r = 0; r < 4; r++) o[mt][nt][r] *= cr[r];
      }
    }
    // p = exp2(s - m); accumulate l; pack 4 keys -> one b64 LDS write
#pragma unroll
    for (int mt = 0; mt < 2; mt++) {
      float rs = 0.f;
#pragma unroll
      for (int kt = 0; kt < 4; kt++) {
#pragma unroll
        for (int r = 0; r < 4; r++) {
          sv[mt][kt][r] = fast_exp2(sv[mt][kt][r] - m_st[mt]);
          rs += sv[mt][kt][r];
        }
        short4 pk;
        pk.x = f2bf(sv[mt][kt][0]); pk.y = f2bf(sv[mt][kt][1]);
        pk.z = f2bf(sv[mt][kt][2]); pk.w = f2bf(sv[mt][kt][3]);
        *(short4*)&Pw[(mt * 16 + lrow) * PST + kt * 16 + lg * 4] = pk;
      }
      rs += __shfl_xor(rs, 16);
      rs += __shfl_xor(rs, 32);
      l_st[mt] += rs;
    }

    // --- PV (V direct from global; loads per-nt to cap VGPR) ---
    bf16x8 pa[2][2];
#pragma unroll
    for (int mt = 0; mt < 2; mt++)
#pragma unroll
      for (int ks = 0; ks < 2; ks++)
        pa[mt][ks] = *(const bf16x8*)&Pw[(mt * 16 + lrow) * PST + ks * 32 + lg * 8];
#pragma unroll
    for (int nt = 0; nt < 5; nt++) {
      bf16x8 vf[2];
#pragma unroll
      for (int ks = 0; ks < 2; ks++)
        vf[ks] = *(const bf16x8*)&vh[(size_t)(nt * 16 + lrow) * SEQ + key0 + ks * 32 + lg * 8];
#pragma unroll
      for (int mt = 0; mt < 2; mt++)
#pragma unroll
        for (int ks = 0; ks < 2; ks++)
          o[mt][nt] = __builtin_amdgcn_mfma_f32_16x16x32_bf16(pa[mt][ks], vf[ks], o[mt][nt], 0, 0, 0);
    }

    __syncthreads();  // drain K stage; all QK reads of Ks[cur] done
  }

#pragma unroll
  for (int mt = 0; mt < 2; mt++) {
    float rl = 1.f / l_st[mt];
    float ir[4];
#pragma unroll
    for (int r = 0; r < 4; r++) ir[r] = __shfl(rl, lg * 4 + r);
#pragma unroll
    for (int r = 0; r < 4; r++) {
      int srow = qbase_s + mt * 16 + lg * 4 + r;
#pragma unroll
      for (int nt = 0; nt < 5; nt++)
        out[(size_t)srow * DIM + h * HD + nt * 16 + lrow] = f2bf(o[mt][nt][r] * ir[r]);
    }
  }
}

extern "C" void kernel_launch(void* const* d_in, const int* in_sizes, int n_in,
                              void* d_out, int out_size, void* d_ws, size_t ws_size,
                              hipStream_t stream) {
  const float* hidden = (const float*)d_in[0];
  const float* cosb = (const float*)d_in[1];
  const float* sinb = (const float*)d_in[2];
  const float* qkv_w = (const float*)d_in[3];
  const float* qkv_b = (const float*)d_in[4];
  const float* proj_w = (const float*)d_in[5];
  const float* proj_b = (const float*)d_in[6];

  char* ws = (char*)d_ws;
  float* qkv_f = (float*)(ws);
  short* attn_o = (short*)(ws);
  short* wp_bf = (short*)(ws + 23068672);
  short* q_bf = (short*)(ws + 125829120);
  short* k_bf = (short*)(ws + 150994944);
  short* v_tb = (short*)(ws + 176160768);
  short* h_bf = (short*)(ws + 197132288);
  short* wq_bf = (short*)(ws + 218103808);

  cast_f32_bf16<<<4096, 256, 0, stream>>>(hidden, h_bf, SEQ * DIM);
  cast_f32_bf16<<<4096, 256, 0, stream>>>(qkv_w, wq_bf, 3 * DIM * DIM);
  gemm_bt_bias<<<dim3(30, 64), 256, 0, stream>>>(h_bf, wq_bf, qkv_b, qkv_f, SEQ, 3 * DIM, DIM);
  rope_qk<<<20480, 256, 0, stream>>>(qkv_f, cosb, sinb, q_bf, k_bf);
  v_transpose<<<dim3(128, 5, 16), 256, 0, stream>>>(qkv_f, v_tb);
  cast_f32_bf16<<<2048, 256, 0, stream>>>(proj_w, wp_bf, DIM * DIM);
  attn_kernel<<<512, 512, 0, stream>>>(q_bf, k_bf, v_tb, attn_o);
  gemm_bt_bias<<<dim3(10, 64), 256, 0, stream>>>(attn_o, wp_bf, proj_b, (float*)d_out, SEQ, DIM, DIM);
}

// Round 9
// 359.354 us; speedup vs baseline: 1.2001x; 1.0009x over previous
//
#include <hip/hip_runtime.h>

#define SEQ 8192
#define DIM 1280
#define NHEADS 16
#define HD 80
#define HDP 96
#define NSEG 8
#define SEG 1024
#define KVB 64
#define NSTEP (SEG / KVB)
#define PST 72

typedef float f32x4 __attribute__((ext_vector_type(4)));
typedef short bf16x8 __attribute__((ext_vector_type(8)));
typedef unsigned int u32;

__device__ __forceinline__ float fast_exp2(float x) {
  return __builtin_amdgcn_exp2f(x);
}

__device__ __forceinline__ short f2bf(float f) {
  unsigned int u = __builtin_bit_cast(unsigned int, f);
  u = (u + 0x7fff + ((u >> 16) & 1)) >> 16;
  return (short)u;
}

typedef __attribute__((address_space(1))) const unsigned int glds_src_t;
typedef __attribute__((address_space(3))) unsigned int glds_dst_t;
__device__ __forceinline__ void gload_lds16(const void* g, void* l) {
  __builtin_amdgcn_global_load_lds((glds_src_t*)g, (glds_dst_t*)l, 16, 0, 0);
}

// ---------------- generic f32 -> bf16 cast (vectorized) ----------------
__global__ void cast_f32_bf16(const float* __restrict__ in, short* __restrict__ out, int n) {
  int n4 = n >> 2;
  for (int i = blockIdx.x * blockDim.x + threadIdx.x; i < n4; i += gridDim.x * blockDim.x) {
    float4 v = ((const float4*)in)[i];
    short4 o;
    o.x = f2bf(v.x); o.y = f2bf(v.y); o.z = f2bf(v.z); o.w = f2bf(v.w);
    ((short4*)out)[i] = o;
  }
}

// ---------------- bf16 GEMM, B^T layout (N,K), f32 out + bias ----------------
// 1D grid (nwg % 8 == 0), XCD swizzle: each XCD owns a contiguous m-chunk
// (A-panel L2-resident). LDS chunk-XOR swizzle (involution, stage-side on
// the global source since global_load_lds writes linearly; same XOR on the
// ds_read side) -> 2-way-max bank aliasing (free) instead of 8-way.
__global__ __launch_bounds__(256) void gemm_bt_bias(
    const short* __restrict__ A, const short* __restrict__ B,
    const float* __restrict__ bias, float* __restrict__ C,
    int M, int N, int K) {
  __shared__ short As[128 * 32];
  __shared__ short Bs[128 * 32];
  int tid = threadIdx.x;
  int w = tid >> 6, l = tid & 63;
  int lrow = l & 15, lg = l >> 4;
  int bid = blockIdx.x;
  int cpx = gridDim.x >> 3;
  int lid = (bid & 7) * cpx + (bid >> 3);  // XCD-contiguous logical id
  int ntx = N >> 7;
  int m0 = (lid / ntx) * 128, n0 = (lid % ntx) * 128;
  int wm = w & 1, wn = w >> 1;

  f32x4 acc[4][4] = {};

  const char* Abase = (const char*)A + (size_t)m0 * K * 2;
  const char* Bbase = (const char*)B + (size_t)n0 * K * 2;

  for (int k0 = 0; k0 < K; k0 += 32) {
#pragma unroll
    for (int j = 0; j < 2; j++) {
      int c = j * 256 + tid;
      int row = c >> 2;
      int slc = (c & 3) ^ ((row >> 1) & 3);  // stage-side swizzle
      size_t goff = (size_t)row * K * 2 + (size_t)k0 * 2 + slc * 16;
      int loff = (j * 256 + w * 64) * 16;
      gload_lds16(Abase + goff, (char*)As + loff);
      gload_lds16(Bbase + goff, (char*)Bs + loff);
    }
    __syncthreads();
    bf16x8 a[4], b[4];
#pragma unroll
    for (int mt = 0; mt < 4; mt++) {
      int row = wm * 64 + mt * 16 + lrow;
      int p = lg ^ ((row >> 1) & 3);
      a[mt] = *(const bf16x8*)&As[row * 32 + p * 8];
    }
#pragma unroll
    for (int nt = 0; nt < 4; nt++) {
      int row = wn * 64 + nt * 16 + lrow;
      int p = lg ^ ((row >> 1) & 3);
      b[nt] = *(const bf16x8*)&Bs[row * 32 + p * 8];
    }
#pragma unroll
    for (int mt = 0; mt < 4; mt++)
#pragma unroll
      for (int nt = 0; nt < 4; nt++)
        acc[mt][nt] = __builtin_amdgcn_mfma_f32_16x16x32_bf16(a[mt], b[nt], acc[mt][nt], 0, 0, 0);
    __syncthreads();
  }
#pragma unroll
  for (int nt = 0; nt < 4; nt++) {
    int col = n0 + wn * 64 + nt * 16 + lrow;
    float bv = bias[col];
#pragma unroll
    for (int mt = 0; mt < 4; mt++) {
      int mrow = m0 + wm * 64 + mt * 16 + lg * 4;
#pragma unroll
      for (int r = 0; r < 4; r++)
        C[(size_t)(mrow + r) * N + col] = acc[mt][nt][r] + bv;
    }
  }
}

// ---------------- RoPE for q,k (f32 in, bf16 out, head-major, pad to 96) ----------------
// q additionally scaled by 80^-0.5 * log2(e) (softmax done in exp2 domain).
__global__ void rope_qk(const float* __restrict__ qkv, const float* __restrict__ cosb,
                        const float* __restrict__ sinb, short* __restrict__ qg,
                        short* __restrict__ kg) {
  int t = blockIdx.x * blockDim.x + threadIdx.x;
  if (t >= SEQ * NHEADS * 40) return;
  int d = t % 40;
  int h = (t / 40) & 15;
  int s = t / 640;
  const float* row = qkv + (size_t)s * (3 * DIM);
  float c0 = cosb[s * HD + d], c1 = cosb[s * HD + d + 40];
  float s0 = sinb[s * HD + d], s1 = sinb[s * HD + d + 40];
  float x1 = row[h * HD + d], x2 = row[h * HD + d + 40];
  float q0 = x1 * c0 - x2 * s0;
  float q1 = x2 * c1 + x1 * s1;
  float y1 = row[DIM + h * HD + d], y2 = row[DIM + h * HD + d + 40];
  float k0 = y1 * c0 - y2 * s0;
  float k1 = y2 * c1 + y1 * s1;
  const float sc = 0.11180339887498949f * 1.4426950408889634f;
  size_t base = ((size_t)h * SEQ + s) * HDP;
  qg[base + d] = f2bf(q0 * sc);
  qg[base + d + 40] = f2bf(q1 * sc);
  kg[base + d] = f2bf(k0);
  kg[base + d + 40] = f2bf(k1);
  if (d < 16) { qg[base + 80 + d] = 0; kg[base + 80 + d] = 0; }
}

// ---------------- V transpose: qkv f32 (S,3,H,80) -> vt bf16 (H,80,S) ----------------
__global__ void v_transpose(const float* __restrict__ qkv, short* __restrict__ vt) {
  __shared__ float T[16][68];
  int st = blockIdx.x, dt = blockIdx.y, h = blockIdx.z;
  int d0 = dt * 16, s0 = st * 64;
  int t = threadIdx.x;
  int dd = t & 15, ss = t >> 4;
#pragma unroll
  for (int j = 0; j < 4; j++) {
    int s = ss + j * 16;
    T[dd][s] = qkv[(size_t)(s0 + s) * (3 * DIM) + 2 * DIM + h * HD + d0 + dd];
  }
  __syncthreads();
  int s2 = t & 63, dr = t >> 6;
#pragma unroll
  for (int j = 0; j < 4; j++) {
    int d = dr + j * 4;
    vt[((size_t)(h * HD + d0 + d)) * SEQ + s0 + s2] = f2bf(T[d][s2]);
  }
}

// ---------------- flash attention v4 (K-LDS cooperative staging) ----------------
// grid 512, 512 threads (8 waves x 32 q-rows). K double-buffered in LDS,
// staged cooperatively via global_load_lds (linear LDS dest + XOR-swizzled
// global source; read applies the same XOR). V direct from global (L2).
// One barrier per iteration.
__global__ __launch_bounds__(512, 4) void attn_kernel(
    const short* __restrict__ qg, const short* __restrict__ kg,
    const short* __restrict__ vt, short* __restrict__ out) {
  __shared__ short Ks[2][64 * 128];  // 32 KB (rows padded 96->128 shorts)
  __shared__ short Pl[8][32 * PST];  // 36 KB
  int bid = blockIdx.x;
  int b = bid & 7, h = (bid >> 3) & 15, qt = bid >> 7;
  int tid = threadIdx.x;
  int w = tid >> 6, l = tid & 63;
  int lrow = l & 15, lg = l >> 4;
  int qbase_s = b * SEG + qt * 256 + w * 32;

  const short* qh = qg + (size_t)h * SEQ * HDP;
  const short* kh = kg + (size_t)h * SEQ * HDP;
  const short* vh = vt + (size_t)h * HD * SEQ;

#define STAGE_K(BUF, KEY0N)                                                    \
  {                                                                            \
    _Pragma("unroll") for (int sr = 0; sr < 2; sr++) {                         \
      int sbase = sr * 512 + w * 64;                                           \
      int ss = sbase + l;                                                      \
      int skey = ss >> 4, sc = ss & 15;                                        \
      int slc = sc ^ (skey & 7);                                               \
      const short* ssrc =                                                      \
          kh + (size_t)((KEY0N) + skey) * HDP + (slc < 12 ? slc * 8 : 0);      \
      gload_lds16(ssrc, (char*)&Ks[BUF][0] + sbase * 16);                      \
    }                                                                          \
  }

  bf16x8 qf[2][3];
#pragma unroll
  for (int mt = 0; mt < 2; mt++)
#pragma unroll
    for (int ks = 0; ks < 3; ks++)
      qf[mt][ks] = *(const bf16x8*)&qh[(size_t)(qbase_s + mt * 16 + lrow) * HDP + ks * 32 + lg * 8];

  f32x4 o[2][5] = {};
  float m_st[2] = {-1e30f, -1e30f};
  float l_st[2] = {0.f, 0.f};

  short* Pw = &Pl[w][0];

  STAGE_K(0, b * SEG);
  __syncthreads();

  for (int i = 0; i < NSTEP; i++) {
    int cur = i & 1;
    int key0 = b * SEG + i * KVB;
    if (i + 1 < NSTEP) {
      STAGE_K(cur ^ 1, key0 + KVB);
    }

    // --- QK^T (swapped: mfma(K,Q), col=query, key in-lane) from LDS ---
    f32x4 sv[2][4] = {};
#pragma unroll
    for (int kt = 0; kt < 4; kt++) {
      bf16x8 kf[3];
      int key = kt * 16 + lrow;
#pragma unroll
      for (int ks = 0; ks < 3; ks++) {
        int p = (ks * 4 + lg) ^ (key & 7);
        kf[ks] = *(const bf16x8*)&Ks[cur][key * 128 + p * 8];
      }
#pragma unroll
      for (int mt = 0; mt < 2; mt++)
#pragma unroll
        for (int ks = 0; ks < 3; ks++)
          sv[mt][kt] = __builtin_amdgcn_mfma_f32_16x16x32_bf16(kf[ks], qf[mt][ks], sv[mt][kt], 0, 0, 0);
    }

    // --- per-query tile max: in-lane over 16 keys, then 2 shfl ---
    float cm[2];
#pragma unroll
    for (int mt = 0; mt < 2; mt++) {
      float a0 = fmaxf(fmaxf(sv[mt][0][0], sv[mt][0][1]), fmaxf(sv[mt][0][2], sv[mt][0][3]));
      float a1 = fmaxf(fmaxf(sv[mt][1][0], sv[mt][1][1]), fmaxf(sv[mt][1][2], sv[mt][1][3]));
      float a2 = fmaxf(fmaxf(sv[mt][2][0], sv[mt][2][1]), fmaxf(sv[mt][2][2], sv[mt][2][3]));
      float a3 = fmaxf(fmaxf(sv[mt][3][0], sv[mt][3][1]), fmaxf(sv[mt][3][2], sv[mt][3][3]));
      float c = fmaxf(fmaxf(a0, a1), fmaxf(a2, a3));
      c = fmaxf(c, __shfl_xor(c, 16));
      c = fmaxf(c, __shfl_xor(c, 32));
      cm[mt] = c;
    }
    // defer-max: rescale only when max grew by > 8 (log2 units)
    if (__any((cm[0] > m_st[0] + 8.f) || (cm[1] > m_st[1] + 8.f))) {
#pragma unroll
      for (int mt = 0; mt < 2; mt++) {
        float mn = fmaxf(m_st[mt], cm[mt]);
        float c = fast_exp2(m_st[mt] - mn);
        m_st[mt] = mn;
        l_st[mt] *= c;
        float cr[4];
#pragma unroll
        for (int r = 0; r < 4; r++) cr[r] = __shfl(c, lg * 4 + r);
#pragma unroll
        for (int nt = 0; nt < 5; nt++)
#pragma unroll
          for (int r = 0; r < 4; r++) o[mt][nt][r] *= cr[r];
      }
    }
    // p = exp2(s - m); accumulate l; pack 4 keys -> one b64 LDS write
#pragma unroll
    for (int mt = 0; mt < 2; mt++) {
      float rs = 0.f;
#pragma unroll
      for (int kt = 0; kt < 4; kt++) {
#pragma unroll
        for (int r = 0; r < 4; r++) {
          sv[mt][kt][r] = fast_exp2(sv[mt][kt][r] - m_st[mt]);
          rs += sv[mt][kt][r];
        }
        short4 pk;
        pk.x = f2bf(sv[mt][kt][0]); pk.y = f2bf(sv[mt][kt][1]);
        pk.z = f2bf(sv[mt][kt][2]); pk.w = f2bf(sv[mt][kt][3]);
        *(short4*)&Pw[(mt * 16 + lrow) * PST + kt * 16 + lg * 4] = pk;
      }
      rs += __shfl_xor(rs, 16);
      rs += __shfl_xor(rs, 32);
      l_st[mt] += rs;
    }

    // --- PV (V direct from global; loads per-nt to cap VGPR) ---
    bf16x8 pa[2][2];
#pragma unroll
    for (int mt = 0; mt < 2; mt++)
#pragma unroll
      for (int ks = 0; ks < 2; ks++)
        pa[mt][ks] = *(const bf16x8*)&Pw[(mt * 16 + lrow) * PST + ks * 32 + lg * 8];
#pragma unroll
    for (int nt = 0; nt < 5; nt++) {
      bf16x8 vf[2];
#pragma unroll
      for (int ks = 0; ks < 2; ks++)
        vf[ks] = *(const bf16x8*)&vh[(size_t)(nt * 16 + lrow) * SEQ + key0 + ks * 32 + lg * 8];
#pragma unroll
      for (int mt = 0; mt < 2; mt++)
#pragma unroll
        for (int ks = 0; ks < 2; ks++)
          o[mt][nt] = __builtin_amdgcn_mfma_f32_16x16x32_bf16(pa[mt][ks], vf[ks], o[mt][nt], 0, 0, 0);
    }

    __syncthreads();  // drain K stage; all QK reads of Ks[cur] done
  }

#pragma unroll
  for (int mt = 0; mt < 2; mt++) {
    float rl = 1.f / l_st[mt];
    float ir[4];
#pragma unroll
    for (int r = 0; r < 4; r++) ir[r] = __shfl(rl, lg * 4 + r);
#pragma unroll
    for (int r = 0; r < 4; r++) {
      int srow = qbase_s + mt * 16 + lg * 4 + r;
#pragma unroll
      for (int nt = 0; nt < 5; nt++)
        out[(size_t)srow * DIM + h * HD + nt * 16 + lrow] = f2bf(o[mt][nt][r] * ir[r]);
    }
  }
}

extern "C" void kernel_launch(void* const* d_in, const int* in_sizes, int n_in,
                              void* d_out, int out_size, void* d_ws, size_t ws_size,
                              hipStream_t stream) {
  const float* hidden = (const float*)d_in[0];
  const float* cosb = (const float*)d_in[1];
  const float* sinb = (const float*)d_in[2];
  const float* qkv_w = (const float*)d_in[3];
  const float* qkv_b = (const float*)d_in[4];
  const float* proj_w = (const float*)d_in[5];
  const float* proj_b = (const float*)d_in[6];

  char* ws = (char*)d_ws;
  float* qkv_f = (float*)(ws);
  short* attn_o = (short*)(ws);
  short* wp_bf = (short*)(ws + 23068672);
  short* q_bf = (short*)(ws + 125829120);
  short* k_bf = (short*)(ws + 150994944);
  short* v_tb = (short*)(ws + 176160768);
  short* h_bf = (short*)(ws + 197132288);
  short* wq_bf = (short*)(ws + 218103808);

  cast_f32_bf16<<<4096, 256, 0, stream>>>(hidden, h_bf, SEQ * DIM);
  cast_f32_bf16<<<4096, 256, 0, stream>>>(qkv_w, wq_bf, 3 * DIM * DIM);
  gemm_bt_bias<<<1920, 256, 0, stream>>>(h_bf, wq_bf, qkv_b, qkv_f, SEQ, 3 * DIM, DIM);
  rope_qk<<<20480, 256, 0, stream>>>(qkv_f, cosb, sinb, q_bf, k_bf);
  v_transpose<<<dim3(128, 5, 16), 256, 0, stream>>>(qkv_f, v_tb);
  cast_f32_bf16<<<2048, 256, 0, stream>>>(proj_w, wp_bf, DIM * DIM);
  attn_kernel<<<512, 512, 0, stream>>>(q_bf, k_bf, v_tb, attn_o);
  gemm_bt_bias<<<640, 256, 0, stream>>>(attn_o, wp_bf, proj_b, (float*)d_out, SEQ, DIM, DIM);
}